// Round 6
// baseline (4018.093 us; speedup 1.0000x reference)
//
#include <hip/hip_runtime.h>

// LSTMFromEmbeddings: B=128, T=1024, E=256, H=256, C=2, bidirectional + meanpool + linear.
//
// R6: two independent chains per wg (same dir, two batch-blocks) interleaved so each
// chain's publish->poll exchange window (~700ns to fabric/L3 and back) is hidden under
// the OTHER chain's MFMA+elementwise. Per-chain sync scheme (tagged 64b agent-scope
// words, parity double buffer) identical to the proven R3/R5 code.
//  rec: 32 persistent wgs = 16 chain-groups (2 dir x 8 batch-blocks of 16) x 4 members
//       (64 units each); W_ih/W_hh fragments in registers (shared by both chains).
//  head: out = (hsum/1024) @ W_lin^T + b_lin.

#define B_ 128
#define T_ 1024
#define E_ 256
#define H_ 256

typedef short short8 __attribute__((ext_vector_type(8)));
typedef float f32x4 __attribute__((ext_vector_type(4)));

__device__ __forceinline__ unsigned short f2bf(float f) {
  unsigned u = __builtin_bit_cast(unsigned, f);
  u += 0x7fffu + ((u >> 16) & 1u);  // RNE
  return (unsigned short)(u >> 16);
}
__device__ __forceinline__ f32x4 mfma16(short8 a, short8 b, f32x4 c) {
  return __builtin_amdgcn_mfma_f32_16x16x32_bf16(a, b, c, 0, 0, 0);
}
__device__ __forceinline__ float sigmf(float x) { return 1.0f / (1.0f + __expf(-x)); }
__device__ __forceinline__ float tanhfast(float x) { return 2.0f / (1.0f + __expf(-2.0f * x)) - 1.0f; }

__device__ __forceinline__ short8 cvt8(f32x4 v0, f32x4 v1) {
  short8 o;
  o[0] = (short)f2bf(v0[0]); o[1] = (short)f2bf(v0[1]);
  o[2] = (short)f2bf(v0[2]); o[3] = (short)f2bf(v0[3]);
  o[4] = (short)f2bf(v1[0]); o[5] = (short)f2bf(v1[1]);
  o[6] = (short)f2bf(v1[2]); o[7] = (short)f2bf(v1[3]);
  return o;
}

// raw barrier: waits LDS ops only; global loads/stores stay in flight.
__device__ __forceinline__ void bar_lds() {
  asm volatile("s_waitcnt lgkmcnt(0)" ::: "memory");
  __builtin_amdgcn_s_barrier();
}

// ---------------- rec: dual-chain fused projection + recurrence ---------------
// grid 32, 512 threads. g8 = bid & 7 -> (dir, pair); member m = bid >> 3 (members
// co-XCD heuristic: bids congruent mod 8). Member m owns units [m*64, m*64+64).
// Chains: A = batch-block 2*pair, B = batch-block 2*pair+1 (both dir d).
__global__ __launch_bounds__(512, 1) void rec_kernel(
    const float* __restrict__ x, const float* __restrict__ mask,
    const float* __restrict__ WihF, const float* __restrict__ WhhF,
    const float* __restrict__ bF, const float* __restrict__ WihB,
    const float* __restrict__ WhhB, const float* __restrict__ bB,
    unsigned long long* __restrict__ Hbuf, float* __restrict__ hsum) {
  __shared__ __align__(16) short XSa[16 * 256], XSb[16 * 256];  // x stage (8KB each)
  __shared__ __align__(16) short HSa[16 * 256], HSb[16 * 256];  // h stage (8KB each)
  __shared__ __align__(16) float gLa[16 * 260], gLb[16 * 260];  // gates (16.6KB each)

  const int bid = blockIdx.x;
  const int g8 = bid & 7, m = bid >> 3;
  const int d = g8 >> 2, pairk = g8 & 3;
  const int bblkA = pairk * 2, bblkB = pairk * 2 + 1;
  const int grpA = d * 8 + bblkA, grpB = d * 8 + bblkB;
  const int tid = threadIdx.x;
  const int w = tid >> 6, l = tid & 63, l15 = l & 15, l4 = l >> 4;
  const int sr = tid >> 5, sc = tid & 31;
  const int ej2 = sc * 2;
  const int gbA = bblkA * 16 + sr, gbB = bblkB * 16 + sr;

  const float* Wih = d ? WihB : WihF;
  const float* Whh = d ? WhhB : WhhF;
  const float* bias = d ? bB : bF;

  // ---- weight fragments -> registers (shared by both chains) ----
  short8 wi[2][8], wh[2][8];
#pragma unroll
  for (int i = 0; i < 2; ++i) {
    int cp = (2 * w + i) * 16 + l15;
    int gate = cp >> 6, ul = cp & 63;
    size_t nat = (size_t)(gate * 256 + m * 64 + ul);
#pragma unroll
    for (int kb = 0; kb < 8; ++kb) {
      const f32x4* pi = (const f32x4*)(Wih + nat * E_ + kb * 32 + l4 * 8);
      wi[i][kb] = cvt8(pi[0], pi[1]);
      const f32x4* ph = (const f32x4*)(Whh + nat * H_ + kb * 32 + l4 * 8);
      wh[i][kb] = cvt8(ph[0], ph[1]);
    }
  }

  const int ub = m * 64 + ej2;
  const float bI0 = bias[ub], bI1 = bias[ub + 1];
  const float bF0 = bias[256 + ub], bF1 = bias[256 + ub + 1];
  const float bG0 = bias[512 + ub], bG1 = bias[512 + ub + 1];
  const float bO0 = bias[768 + ub], bO1 = bias[768 + ub + 1];

  // ---- prologue: stage x_0 for both chains, acc = xg_0 ----
  {
    int ts = d ? (T_ - 1) : 0;
    const f32x4* pa = (const f32x4*)(x + ((size_t)gbA * T_ + ts) * E_ + sc * 8);
    float ma = mask[(size_t)gbA * T_ + ts];
    ((short8*)XSa)[sr * 32 + (sc ^ (sr & 7))] = cvt8(pa[0] * ma, pa[1] * ma);
    const f32x4* pb = (const f32x4*)(x + ((size_t)gbB * T_ + ts) * E_ + sc * 8);
    float mb = mask[(size_t)gbB * T_ + ts];
    ((short8*)XSb)[sr * 32 + (sc ^ (sr & 7))] = cvt8(pb[0] * mb, pb[1] * mb);
  }
  __syncthreads();
  f32x4 accA[2] = {}, accB[2] = {};
#pragma unroll
  for (int kb = 0; kb < 8; ++kb) {
    short8 aa = ((short8*)XSa)[l15 * 32 + ((kb * 4 + l4) ^ (l15 & 7))];
    accA[0] = mfma16(aa, wi[0][kb], accA[0]);
    accA[1] = mfma16(aa, wi[1][kb], accA[1]);
    short8 ab = ((short8*)XSb)[l15 * 32 + ((kb * 4 + l4) ^ (l15 & 7))];
    accB[0] = mfma16(ab, wi[0][kb], accB[0]);
    accB[1] = mfma16(ab, wi[1][kb], accB[1]);
  }
  __syncthreads();

  float csA0 = 0.f, csA1 = 0.f, hsA0 = 0.f, hsA1 = 0.f;
  float csB0 = 0.f, csB1 = 0.f, hsB0 = 0.f, hsB1 = 0.f;

  for (int t = 0; t < T_; ++t) {
    const bool more = (t + 1 < T_);
    const unsigned tag = (unsigned)(t + 1);
    const size_t baseA = ((size_t)grpA * 2 + (tag & 1)) * 16;
    const size_t baseB = ((size_t)grpB * 2 + (tag & 1)) * 16;

    // ---------------- phase A: chain A compute ----------------
    f32x4 xa0, xa1;
    float mka = 0.f;
    if (more) {
      int ts = d ? (T_ - 2 - t) : (t + 1);
      const f32x4* px = (const f32x4*)(x + ((size_t)gbA * T_ + ts) * E_ + sc * 8);
      xa0 = px[0]; xa1 = px[1];
      mka = mask[(size_t)gbA * T_ + ts];
    }
    if (t > 0) {
#pragma unroll
      for (int kb = 0; kb < 8; ++kb) {
        short8 a = ((short8*)HSa)[l15 * 32 + ((kb * 4 + l4) ^ (l15 & 7))];
        accA[0] = mfma16(a, wh[0][kb], accA[0]);
        accA[1] = mfma16(a, wh[1][kb], accA[1]);
      }
    }
#pragma unroll
    for (int i = 0; i < 2; ++i)
#pragma unroll
      for (int r = 0; r < 4; ++r)
        gLa[(l4 * 4 + r) * 260 + (2 * w + i) * 16 + l15] = accA[i][r];
    bar_lds();  // gates A visible

    float h0A, h1A;
    {
      float gi0 = gLa[sr * 260 + ej2] + bI0;
      float gf0 = gLa[sr * 260 + 64 + ej2] + bF0;
      float gg0 = gLa[sr * 260 + 128 + ej2] + bG0;
      float go0 = gLa[sr * 260 + 192 + ej2] + bO0;
      float gi1 = gLa[sr * 260 + ej2 + 1] + bI1;
      float gf1 = gLa[sr * 260 + 64 + ej2 + 1] + bF1;
      float gg1 = gLa[sr * 260 + 128 + ej2 + 1] + bG1;
      float go1 = gLa[sr * 260 + 192 + ej2 + 1] + bO1;
      csA0 = sigmf(gf0) * csA0 + sigmf(gi0) * tanhfast(gg0);
      csA1 = sigmf(gf1) * csA1 + sigmf(gi1) * tanhfast(gg1);
      h0A = sigmf(go0) * tanhfast(csA0);
      h1A = sigmf(go1) * tanhfast(csA1);
      hsA0 += h0A; hsA1 += h1A;
    }
    if (more) {  // publish A (fire-and-forget; ack drains during phase B)
      unsigned pay = (unsigned)f2bf(h0A) | ((unsigned)f2bf(h1A) << 16);
      unsigned long long word = (((unsigned long long)tag) << 32) | pay;
      __hip_atomic_store(&Hbuf[(baseA + sr) * 128 + m * 32 + sc], word,
                         __ATOMIC_RELAXED, __HIP_MEMORY_SCOPE_AGENT);
      asm volatile("" ::: "memory");
    }

    // ---------------- phase B: chain B compute ----------------
    f32x4 xb0, xb1;
    float mkb = 0.f;
    if (more) {
      int ts = d ? (T_ - 2 - t) : (t + 1);
      const f32x4* px = (const f32x4*)(x + ((size_t)gbB * T_ + ts) * E_ + sc * 8);
      xb0 = px[0]; xb1 = px[1];
      mkb = mask[(size_t)gbB * T_ + ts];
    }
    if (t > 0) {
#pragma unroll
      for (int kb = 0; kb < 8; ++kb) {
        short8 a = ((short8*)HSb)[l15 * 32 + ((kb * 4 + l4) ^ (l15 & 7))];
        accB[0] = mfma16(a, wh[0][kb], accB[0]);
        accB[1] = mfma16(a, wh[1][kb], accB[1]);
      }
    }
#pragma unroll
    for (int i = 0; i < 2; ++i)
#pragma unroll
      for (int r = 0; r < 4; ++r)
        gLb[(l4 * 4 + r) * 260 + (2 * w + i) * 16 + l15] = accB[i][r];
    bar_lds();  // gates B visible

    float h0B, h1B;
    {
      float gi0 = gLb[sr * 260 + ej2] + bI0;
      float gf0 = gLb[sr * 260 + 64 + ej2] + bF0;
      float gg0 = gLb[sr * 260 + 128 + ej2] + bG0;
      float go0 = gLb[sr * 260 + 192 + ej2] + bO0;
      float gi1 = gLb[sr * 260 + ej2 + 1] + bI1;
      float gf1 = gLb[sr * 260 + 64 + ej2 + 1] + bF1;
      float gg1 = gLb[sr * 260 + 128 + ej2 + 1] + bG1;
      float go1 = gLb[sr * 260 + 192 + ej2 + 1] + bO1;
      csB0 = sigmf(gf0) * csB0 + sigmf(gi0) * tanhfast(gg0);
      csB1 = sigmf(gf1) * csB1 + sigmf(gi1) * tanhfast(gg1);
      h0B = sigmf(go0) * tanhfast(csB0);
      h1B = sigmf(go1) * tanhfast(csB1);
      hsB0 += h0B; hsB1 += h1B;
    }

    unsigned long long vvA[4], vvB[4];
    const unsigned long long* rpA = &Hbuf[(baseA + sr) * 128 + sc * 4];
    const unsigned long long* rpB = &Hbuf[(baseB + sr) * 128 + sc * 4];
    if (more) {
      // poll-issue A BEFORE publish B: the later check waits only up to these loads
      // (in-order vmcnt retirement never covers publish B's slow ack).
#pragma unroll
      for (int j = 0; j < 4; ++j)
        vvA[j] = __hip_atomic_load(&rpA[j], __ATOMIC_RELAXED, __HIP_MEMORY_SCOPE_AGENT);
      asm volatile("" ::: "memory");
      unsigned pay = (unsigned)f2bf(h0B) | ((unsigned)f2bf(h1B) << 16);
      unsigned long long word = (((unsigned long long)tag) << 32) | pay;
      __hip_atomic_store(&Hbuf[(baseB + sr) * 128 + m * 32 + sc], word,
                         __ATOMIC_RELAXED, __HIP_MEMORY_SCOPE_AGENT);
      asm volatile("" ::: "memory");
    }

    // ---------------- phase C: chain A finish ----------------
    if (more) {
      ((short8*)XSa)[sr * 32 + (sc ^ (sr & 7))] = cvt8(xa0 * mka, xa1 * mka);
      bar_lds();  // XSa visible; gLa fully read
      accA[0] = (f32x4){0.f, 0.f, 0.f, 0.f};
      accA[1] = (f32x4){0.f, 0.f, 0.f, 0.f};
#pragma unroll
      for (int kb = 0; kb < 8; ++kb) {
        short8 a = ((short8*)XSa)[l15 * 32 + ((kb * 4 + l4) ^ (l15 & 7))];
        accA[0] = mfma16(a, wi[0][kb], accA[0]);
        accA[1] = mfma16(a, wi[1][kb], accA[1]);
      }
      for (;;) {  // parallel retry rounds
        bool ok = true;
#pragma unroll
        for (int j = 0; j < 4; ++j) ok &= ((unsigned)(vvA[j] >> 32) == tag);
        if (ok) break;
#pragma unroll
        for (int j = 0; j < 4; ++j)
          if ((unsigned)(vvA[j] >> 32) != tag)
            vvA[j] = __hip_atomic_load(&rpA[j], __ATOMIC_RELAXED, __HIP_MEMORY_SCOPE_AGENT);
        asm volatile("" ::: "memory");
      }
      short8 hv;
#pragma unroll
      for (int j = 0; j < 4; ++j) {
        hv[2 * j] = (short)(unsigned short)(vvA[j] & 0xffffu);
        hv[2 * j + 1] = (short)(unsigned short)((vvA[j] >> 16) & 0xffffu);
      }
      ((short8*)HSa)[sr * 32 + (sc ^ (sr & 7))] = hv;
      bar_lds();  // HSa visible; XSa fully read

      // ---------------- phase D: chain B finish ----------------
#pragma unroll
      for (int j = 0; j < 4; ++j)
        vvB[j] = __hip_atomic_load(&rpB[j], __ATOMIC_RELAXED, __HIP_MEMORY_SCOPE_AGENT);
      asm volatile("" ::: "memory");
      ((short8*)XSb)[sr * 32 + (sc ^ (sr & 7))] = cvt8(xb0 * mkb, xb1 * mkb);
      bar_lds();  // XSb visible; gLb fully read
      accB[0] = (f32x4){0.f, 0.f, 0.f, 0.f};
      accB[1] = (f32x4){0.f, 0.f, 0.f, 0.f};
#pragma unroll
      for (int kb = 0; kb < 8; ++kb) {
        short8 a = ((short8*)XSb)[l15 * 32 + ((kb * 4 + l4) ^ (l15 & 7))];
        accB[0] = mfma16(a, wi[0][kb], accB[0]);
        accB[1] = mfma16(a, wi[1][kb], accB[1]);
      }
      for (;;) {
        bool ok = true;
#pragma unroll
        for (int j = 0; j < 4; ++j) ok &= ((unsigned)(vvB[j] >> 32) == tag);
        if (ok) break;
#pragma unroll
        for (int j = 0; j < 4; ++j)
          if ((unsigned)(vvB[j] >> 32) != tag)
            vvB[j] = __hip_atomic_load(&rpB[j], __ATOMIC_RELAXED, __HIP_MEMORY_SCOPE_AGENT);
        asm volatile("" ::: "memory");
      }
#pragma unroll
      for (int j = 0; j < 4; ++j) {
        hv[2 * j] = (short)(unsigned short)(vvB[j] & 0xffffu);
        hv[2 * j + 1] = (short)(unsigned short)((vvB[j] >> 16) & 0xffffu);
      }
      ((short8*)HSb)[sr * 32 + (sc ^ (sr & 7))] = hv;
      bar_lds();  // HSb visible; XSb fully read
    }
  }

  hsum[((size_t)d * B_ + gbA) * H_ + ub] = hsA0;
  hsum[((size_t)d * B_ + gbA) * H_ + ub + 1] = hsA1;
  hsum[((size_t)d * B_ + gbB) * H_ + ub] = hsB0;
  hsum[((size_t)d * B_ + gbB) * H_ + ub + 1] = hsB1;
}

// ---------------- head: linear ----------------------------------------------
__global__ __launch_bounds__(256, 1) void head_kernel(
    const float* __restrict__ hsum, const float* __restrict__ Wlin,
    const float* __restrict__ blin, float* __restrict__ out) {
  int tid = threadIdx.x;  // 256 = 128 b x 2 c
  int b = tid >> 1, c = tid & 1;
  const f32x4* hf = (const f32x4*)(hsum + (size_t)b * H_);
  const f32x4* hbk = (const f32x4*)(hsum + (size_t)B_ * H_ + (size_t)b * H_);
  const f32x4* wl = (const f32x4*)(Wlin + (size_t)c * 512);
  float s = 0.f;
  for (int j = 0; j < 64; ++j) {
    f32x4 a = hf[j], ww = wl[j];
    s += a[0] * ww[0] + a[1] * ww[1] + a[2] * ww[2] + a[3] * ww[3];
  }
  for (int j = 0; j < 64; ++j) {
    f32x4 a = hbk[j], ww = wl[64 + j];
    s += a[0] * ww[0] + a[1] * ww[1] + a[2] * ww[2] + a[3] * ww[3];
  }
  out[tid] = s * (1.0f / 1024.0f) + blin[c];
}

// ---------------- launch -----------------------------------------------------
extern "C" void kernel_launch(void* const* d_in, const int* in_sizes, int n_in,
                              void* d_out, int out_size, void* d_ws, size_t ws_size,
                              hipStream_t stream) {
  const float* emb = (const float*)d_in[0];
  const float* mask = (const float*)d_in[1];
  const float* Wih_f = (const float*)d_in[2];
  const float* Whh_f = (const float*)d_in[3];
  const float* b_f = (const float*)d_in[4];
  const float* Wih_b = (const float*)d_in[5];
  const float* Whh_b = (const float*)d_in[6];
  const float* b_b = (const float*)d_in[7];
  const float* Wlin = (const float*)d_in[8];
  const float* blin = (const float*)d_in[9];
  float* out = (float*)d_out;

  // Hbuf: [16 groups][2 parity][16 batches][128 words] x 8B = 512 KiB
  const size_t HBUF_BYTES = (size_t)16 * 2 * 16 * 128 * 8;
  const size_t HSUM_BYTES = (size_t)2 * B_ * H_ * 4;  // 256 KiB
  if (ws_size < HBUF_BYTES + HSUM_BYTES) return;

  char* ws = (char*)d_ws;
  unsigned long long* Hbuf = (unsigned long long*)ws;
  float* hsum = (float*)(ws + HBUF_BYTES);

  hipMemsetAsync(Hbuf, 0, HBUF_BYTES, stream);  // tags start at 1; replay-safe
  rec_kernel<<<32, 512, 0, stream>>>(emb, mask, Wih_f, Whh_f, b_f,
                                     Wih_b, Whh_b, b_b, Hbuf, hsum);
  head_kernel<<<1, 256, 0, stream>>>(hsum, Wlin, blin, out);
}

// Round 7
// 2165.460 us; speedup vs baseline: 1.8555x; 1.8555x over previous
//
#include <hip/hip_runtime.h>

// LSTMFromEmbeddings: B=128, T=1024, E=256, H=256, C=2, bidirectional + meanpool + linear.
//
// R7: cut per-step VALU (measured: step time was compute-dominated, ~34% local VALUBusy).
//  prep: x_img[bblk][t] = 8KB LDS-image of bf16(x*mask), row/chunk swizzle pre-applied,
//        so rec stages x via ONE global_load_lds (dwordx4) per thread per step.
//  rec:  64 persistent wgs = 16 groups (2 dir x 8 batch-blocks of 16) x 4 members
//        (64 units each); weights in registers. 2 barriers/step. Publish/poll via
//        tagged agent-scope 64b words (proven R3 scheme), late poll, batched retry.
//  head: out = (hsum/1024) @ W_lin^T + b_lin.
//  Fallback (ws too small for the 64MB image): same kernel, in-loop staging, 3 barriers.

#define B_ 128
#define T_ 1024
#define E_ 256
#define H_ 256

typedef short short8 __attribute__((ext_vector_type(8)));
typedef float f32x4 __attribute__((ext_vector_type(4)));

__device__ __forceinline__ unsigned short f2bf(float f) {
  unsigned u = __builtin_bit_cast(unsigned, f);
  u += 0x7fffu + ((u >> 16) & 1u);  // RNE
  return (unsigned short)(u >> 16);
}
__device__ __forceinline__ f32x4 mfma16(short8 a, short8 b, f32x4 c) {
  return __builtin_amdgcn_mfma_f32_16x16x32_bf16(a, b, c, 0, 0, 0);
}
__device__ __forceinline__ float sigmf(float x) { return 1.0f / (1.0f + __expf(-x)); }
__device__ __forceinline__ float tanhfast(float x) { return 2.0f / (1.0f + __expf(-2.0f * x)) - 1.0f; }

__device__ __forceinline__ short8 cvt8(f32x4 v0, f32x4 v1) {
  short8 o;
  o[0] = (short)f2bf(v0[0]); o[1] = (short)f2bf(v0[1]);
  o[2] = (short)f2bf(v0[2]); o[3] = (short)f2bf(v0[3]);
  o[4] = (short)f2bf(v1[0]); o[5] = (short)f2bf(v1[1]);
  o[6] = (short)f2bf(v1[2]); o[7] = (short)f2bf(v1[3]);
  return o;
}

__device__ __forceinline__ void bar_lds() {  // LDS-only barrier; vmem stays in flight
  asm volatile("s_waitcnt lgkmcnt(0)" ::: "memory");
  __builtin_amdgcn_s_barrier();
}

__device__ __forceinline__ void gload16(const void* g, void* l) {
  __builtin_amdgcn_global_load_lds(
      (const __attribute__((address_space(1))) void*)g,
      (__attribute__((address_space(3))) void*)l, 16, 0, 0);
}

// ---------------- prep: x image in LDS-tile layout ---------------------------
// word gid = ((bblk*1024 + t)*512 + i), i = r*32 + s; holds bf16x8 of
// x[bblk*16+r][t][k-chunk (s ^ (r&7))] * mask. 4,194,304 words = 64 MiB.
__global__ __launch_bounds__(256, 4) void prep_kernel(
    const float* __restrict__ x, const float* __restrict__ mask,
    unsigned short* __restrict__ img) {
  int gid = blockIdx.x * 256 + threadIdx.x;
  int i = gid & 511;
  int tt = (gid >> 9) & 1023;
  int bblk = gid >> 19;
  int r = i >> 5, s = i & 31, kc = s ^ (r & 7);
  int b = bblk * 16 + r;
  const f32x4* src = (const f32x4*)(x + ((size_t)b * T_ + tt) * E_ + kc * 8);
  float mk = mask[(size_t)b * T_ + tt];
  ((short8*)img)[gid] = cvt8(src[0] * mk, src[1] * mk);
}

// ---------------- rec: fused projection + recurrence --------------------------
// grid 64, 512 threads. group g = bid & 15, member m = bid >> 4 (members co-XCD
// heuristic: bids congruent mod 8). Member m owns units [m*64, m*64+64).
template <bool PREP>
__global__ __launch_bounds__(512, 1) void rec_kernel(
    const float* __restrict__ x, const float* __restrict__ mask,
    const unsigned short* __restrict__ img,
    const float* __restrict__ WihF, const float* __restrict__ WhhF,
    const float* __restrict__ bF, const float* __restrict__ WihB,
    const float* __restrict__ WhhB, const float* __restrict__ bB,
    unsigned long long* __restrict__ Hbuf, float* __restrict__ hsum) {
  __shared__ __align__(16) short XS[2][16 * 256];  // x stage, parity dbuf (16KB)
  __shared__ __align__(16) short HS[16 * 256];     // h stage (8KB)
  __shared__ __align__(16) float gatesL[16 * 260]; // gates fp32, +4 pad (16.6KB)

  const int bid = blockIdx.x;
  const int g = bid & 15, m = bid >> 4;
  const int d = g >> 3, bblk = g & 7;
  const int tid = threadIdx.x;
  const int w = tid >> 6, l = tid & 63, l15 = l & 15, l4 = l >> 4;
  const int sr = tid >> 5, sc = tid & 31;
  const int ej2 = sc * 2;
  const int gb = bblk * 16 + sr;

  const float* Wih = d ? WihB : WihF;
  const float* Whh = d ? WhhB : WhhF;
  const float* bias = d ? bB : bF;

  // weight fragments -> registers
  short8 wi[2][8], wh[2][8];
#pragma unroll
  for (int i = 0; i < 2; ++i) {
    int cp = (2 * w + i) * 16 + l15;
    int gate = cp >> 6, ul = cp & 63;
    size_t nat = (size_t)(gate * 256 + m * 64 + ul);
#pragma unroll
    for (int kb = 0; kb < 8; ++kb) {
      const f32x4* pi = (const f32x4*)(Wih + nat * E_ + kb * 32 + l4 * 8);
      wi[i][kb] = cvt8(pi[0], pi[1]);
      const f32x4* ph = (const f32x4*)(Whh + nat * H_ + kb * 32 + l4 * 8);
      wh[i][kb] = cvt8(ph[0], ph[1]);
    }
  }

  const int ub = m * 64 + ej2;
  const float bI0 = bias[ub], bI1 = bias[ub + 1];
  const float bF0 = bias[256 + ub], bF1 = bias[256 + ub + 1];
  const float bG0 = bias[512 + ub], bG1 = bias[512 + ub + 1];
  const float bO0 = bias[768 + ub], bO1 = bias[768 + ub + 1];

  // x source pointer (image bytes), step = +-8KB per t
  const int dstep = d ? -8192 : 8192;
  const char* gsrc = (const char*)img +
      ((size_t)(bblk * 1024 + (d ? (T_ - 1) : 0)) * 8192) + (size_t)tid * 16;

  // ---- prologue: stage x_0 into XS[0], acc = xg_0 ----
  if constexpr (PREP) {
    gload16(gsrc, (char*)XS[0] + w * 1024);
    gsrc += dstep;
  } else {
    int ts = d ? (T_ - 1) : 0;
    const f32x4* px = (const f32x4*)(x + ((size_t)gb * T_ + ts) * E_ + sc * 8);
    float mk = mask[(size_t)gb * T_ + ts];
    ((short8*)XS[0])[sr * 32 + (sc ^ (sr & 7))] = cvt8(px[0] * mk, px[1] * mk);
  }
  __syncthreads();
  f32x4 acc[2] = {}, accB[2] = {};
#pragma unroll
  for (int kp = 0; kp < 4; ++kp) {
    short8 a0 = ((short8*)XS[0])[l15 * 32 + ((kp * 8 + l4) ^ (l15 & 7))];
    acc[0] = mfma16(a0, wi[0][2 * kp], acc[0]);
    acc[1] = mfma16(a0, wi[1][2 * kp], acc[1]);
    short8 a1 = ((short8*)XS[0])[l15 * 32 + ((kp * 8 + 4 + l4) ^ (l15 & 7))];
    accB[0] = mfma16(a1, wi[0][2 * kp + 1], accB[0]);
    accB[1] = mfma16(a1, wi[1][2 * kp + 1], accB[1]);
  }
  __syncthreads();  // XS[0] consumed before any rewrite

  float cs0 = 0.f, cs1 = 0.f, hs0 = 0.f, hs1 = 0.f;

  for (int t = 0; t < T_; ++t) {
    const bool more = (t + 1 < T_);
    char* xsN = (char*)XS[(t + 1) & 1];

    f32x4 xv0, xv1;
    float mk = 0.f;
    if (more) {
      if constexpr (PREP) {
        gload16(gsrc, xsN + w * 1024);  // async -> drained by the __syncthreads below
        gsrc += dstep;
      } else {
        int ts = d ? (T_ - 2 - t) : (t + 1);
        const f32x4* px = (const f32x4*)(x + ((size_t)gb * T_ + ts) * E_ + sc * 8);
        xv0 = px[0]; xv1 = px[1];
        mk = mask[(size_t)gb * T_ + ts];
      }
    }

    // hh product into acc (acc holds xg_t)
    if (t > 0) {
#pragma unroll
      for (int kp = 0; kp < 4; ++kp) {
        short8 a0 = ((short8*)HS)[l15 * 32 + ((kp * 8 + l4) ^ (l15 & 7))];
        acc[0] = mfma16(a0, wh[0][2 * kp], acc[0]);
        acc[1] = mfma16(a0, wh[1][2 * kp], acc[1]);
        short8 a1 = ((short8*)HS)[l15 * 32 + ((kp * 8 + 4 + l4) ^ (l15 & 7))];
        accB[0] = mfma16(a1, wh[0][2 * kp + 1], accB[0]);
        accB[1] = mfma16(a1, wh[1][2 * kp + 1], accB[1]);
      }
    }

    // gates -> LDS. D layout: row(batch)=l4*4+r, col'=(2w+i)*16+l15
#pragma unroll
    for (int i = 0; i < 2; ++i)
#pragma unroll
      for (int r = 0; r < 4; ++r)
        gatesL[(l4 * 4 + r) * 260 + (2 * w + i) * 16 + l15] = acc[i][r] + accB[i][r];

    if constexpr (PREP) {
      __syncthreads();  // gates visible AND this iter's gload_lds complete
    } else {
      bar_lds();        // gates visible (x still in regs)
    }

    // fp32 LSTM elementwise: 2 units, batch sr
    float gi0 = gatesL[sr * 260 + ej2] + bI0;
    float gf0 = gatesL[sr * 260 + 64 + ej2] + bF0;
    float gg0 = gatesL[sr * 260 + 128 + ej2] + bG0;
    float go0 = gatesL[sr * 260 + 192 + ej2] + bO0;
    float gi1 = gatesL[sr * 260 + ej2 + 1] + bI1;
    float gf1 = gatesL[sr * 260 + 64 + ej2 + 1] + bF1;
    float gg1 = gatesL[sr * 260 + 128 + ej2 + 1] + bG1;
    float go1 = gatesL[sr * 260 + 192 + ej2 + 1] + bO1;
    cs0 = sigmf(gf0) * cs0 + sigmf(gi0) * tanhfast(gg0);
    cs1 = sigmf(gf1) * cs1 + sigmf(gi1) * tanhfast(gg1);
    float h0 = sigmf(go0) * tanhfast(cs0);
    float h1 = sigmf(go1) * tanhfast(cs1);
    hs0 += h0;
    hs1 += h1;

    if (more) {
      const unsigned tag = (unsigned)(t + 1);
      const size_t base = ((size_t)g * 2 + (tag & 1)) * 16;  // [grp][parity][16b][128w]

      // publish own slice (1 packed cvt + fire-and-forget store)
      unsigned pay;
      asm("v_cvt_pk_bf16_f32 %0, %1, %2" : "=v"(pay) : "v"(h0), "v"(h1));
      unsigned long long word = (((unsigned long long)tag) << 32) | (unsigned long long)pay;
      __hip_atomic_store(&Hbuf[(base + sr) * 128 + m * 32 + sc], word,
                         __ATOMIC_RELAXED, __HIP_MEMORY_SCOPE_AGENT);
      asm volatile("" ::: "memory");

      if constexpr (!PREP) {
        ((short8*)XS[(t + 1) & 1])[sr * 32 + (sc ^ (sr & 7))] = cvt8(xv0 * mk, xv1 * mk);
        bar_lds();  // XS visible (PREP path already synced it)
      }

      // acc = xg_{t+1} (fills the publish->visibility window)
      acc[0] = (f32x4){0.f, 0.f, 0.f, 0.f};
      acc[1] = (f32x4){0.f, 0.f, 0.f, 0.f};
      accB[0] = (f32x4){0.f, 0.f, 0.f, 0.f};
      accB[1] = (f32x4){0.f, 0.f, 0.f, 0.f};
#pragma unroll
      for (int kp = 0; kp < 4; ++kp) {
        short8 a0 = ((short8*)xsN)[l15 * 32 + ((kp * 8 + l4) ^ (l15 & 7))];
        acc[0] = mfma16(a0, wi[0][2 * kp], acc[0]);
        acc[1] = mfma16(a0, wi[1][2 * kp], acc[1]);
        short8 a1 = ((short8*)xsN)[l15 * 32 + ((kp * 8 + 4 + l4) ^ (l15 & 7))];
        accB[0] = mfma16(a1, wi[0][2 * kp + 1], accB[0]);
        accB[1] = mfma16(a1, wi[1][2 * kp + 1], accB[1]);
      }

      // late poll: issue all 4, batched parallel retry
      const unsigned long long* rp = &Hbuf[(base + sr) * 128 + sc * 4];
      unsigned long long vv[4];
#pragma unroll
      for (int j = 0; j < 4; ++j)
        vv[j] = __hip_atomic_load(&rp[j], __ATOMIC_RELAXED, __HIP_MEMORY_SCOPE_AGENT);
      asm volatile("" ::: "memory");
      for (;;) {
        bool ok = true;
#pragma unroll
        for (int j = 0; j < 4; ++j) ok &= ((unsigned)(vv[j] >> 32) == tag);
        if (ok) break;
#pragma unroll
        for (int j = 0; j < 4; ++j)
          if ((unsigned)(vv[j] >> 32) != tag)
            vv[j] = __hip_atomic_load(&rp[j], __ATOMIC_RELAXED, __HIP_MEMORY_SCOPE_AGENT);
        asm volatile("" ::: "memory");
      }
      // HS row: 4 payload dwords = 8 bf16, one ds_write_b128
      int4 hw;
      hw.x = (int)(unsigned)vv[0]; hw.y = (int)(unsigned)vv[1];
      hw.z = (int)(unsigned)vv[2]; hw.w = (int)(unsigned)vv[3];
      *(int4*)((char*)HS + (size_t)(sr * 32 + (sc ^ (sr & 7))) * 16) = hw;
      bar_lds();  // HS visible; xsN fully read
    }
  }

  hsum[((size_t)d * B_ + gb) * H_ + ub] = hs0;
  hsum[((size_t)d * B_ + gb) * H_ + ub + 1] = hs1;
}

// ---------------- head: linear ----------------------------------------------
__global__ __launch_bounds__(256, 1) void head_kernel(
    const float* __restrict__ hsum, const float* __restrict__ Wlin,
    const float* __restrict__ blin, float* __restrict__ out) {
  int tid = threadIdx.x;  // 256 = 128 b x 2 c
  int b = tid >> 1, c = tid & 1;
  const f32x4* hf = (const f32x4*)(hsum + (size_t)b * H_);
  const f32x4* hbk = (const f32x4*)(hsum + (size_t)B_ * H_ + (size_t)b * H_);
  const f32x4* wl = (const f32x4*)(Wlin + (size_t)c * 512);
  float s = 0.f;
  for (int j = 0; j < 64; ++j) {
    f32x4 a = hf[j], ww = wl[j];
    s += a[0] * ww[0] + a[1] * ww[1] + a[2] * ww[2] + a[3] * ww[3];
  }
  for (int j = 0; j < 64; ++j) {
    f32x4 a = hbk[j], ww = wl[64 + j];
    s += a[0] * ww[0] + a[1] * ww[1] + a[2] * ww[2] + a[3] * ww[3];
  }
  out[tid] = s * (1.0f / 1024.0f) + blin[c];
}

// ---------------- launch -----------------------------------------------------
extern "C" void kernel_launch(void* const* d_in, const int* in_sizes, int n_in,
                              void* d_out, int out_size, void* d_ws, size_t ws_size,
                              hipStream_t stream) {
  const float* emb = (const float*)d_in[0];
  const float* mask = (const float*)d_in[1];
  const float* Wih_f = (const float*)d_in[2];
  const float* Whh_f = (const float*)d_in[3];
  const float* b_f = (const float*)d_in[4];
  const float* Wih_b = (const float*)d_in[5];
  const float* Whh_b = (const float*)d_in[6];
  const float* b_b = (const float*)d_in[7];
  const float* Wlin = (const float*)d_in[8];
  const float* blin = (const float*)d_in[9];
  float* out = (float*)d_out;

  const size_t HBUF_BYTES = (size_t)16 * 2 * 16 * 128 * 8;    // 512 KiB
  const size_t HSUM_BYTES = (size_t)2 * B_ * H_ * 4;          // 256 KiB
  const size_t IMG_BYTES = (size_t)8 * 1024 * 512 * 16;       // 64 MiB
  if (ws_size < HBUF_BYTES + HSUM_BYTES) return;
  const bool prep = ws_size >= HBUF_BYTES + HSUM_BYTES + IMG_BYTES;

  char* ws = (char*)d_ws;
  unsigned long long* Hbuf = (unsigned long long*)ws;
  float* hsum = (float*)(ws + HBUF_BYTES);
  unsigned short* img = (unsigned short*)(ws + HBUF_BYTES + HSUM_BYTES);

  hipMemsetAsync(Hbuf, 0, HBUF_BYTES, stream);  // tags start at 1; replay-safe
  if (prep) {
    prep_kernel<<<16384, 256, 0, stream>>>(emb, mask, img);
    rec_kernel<true><<<64, 512, 0, stream>>>(emb, mask, img, Wih_f, Whh_f, b_f,
                                             Wih_b, Whh_b, b_b, Hbuf, hsum);
  } else {
    rec_kernel<false><<<64, 512, 0, stream>>>(emb, mask, img, Wih_f, Whh_f, b_f,
                                              Wih_b, Whh_b, b_b, Hbuf, hsum);
  }
  head_kernel<<<1, 256, 0, stream>>>(hsum, Wlin, blin, out);
}

// Round 8
// 1941.204 us; speedup vs baseline: 2.0699x; 1.1155x over previous
//
#include <hip/hip_runtime.h>

// LSTMFromEmbeddings: B=128, T=1024, E=256, H=256, C=2, bidirectional + meanpool + linear.
//
// R8: remove all vmem drains from the recurrence loop + cheap transcendentals.
//  - x prefetched TWO steps ahead via global_load_lds into XS parity slots; by in-order
//    vmcnt retirement, the previous step's poll-wait already covers gload(t+1), so the
//    loop needs only lgkm-only barriers (2/step), no vmcnt(0) drains.
//  - elementwise: explicit v_rcp (not IEEE div), merged reciprocals (3 rcp + 5 exp per
//    unit), bias folded into MFMA acc init, float2 gate reads.
//  - publish/poll: proven tagged agent-scope 64b word scheme (R3/R7), batched retry.
//  rec: 64 persistent wgs = 16 groups (2 dir x 8 batch-blocks of 16) x 4 members.
//  head: out = (hsum/1024) @ W_lin^T + b_lin.

#define B_ 128
#define T_ 1024
#define E_ 256
#define H_ 256

typedef short short8 __attribute__((ext_vector_type(8)));
typedef float f32x4 __attribute__((ext_vector_type(4)));
typedef float f32x2 __attribute__((ext_vector_type(2)));

__device__ __forceinline__ unsigned short f2bf(float f) {
  unsigned u = __builtin_bit_cast(unsigned, f);
  u += 0x7fffu + ((u >> 16) & 1u);  // RNE
  return (unsigned short)(u >> 16);
}
__device__ __forceinline__ f32x4 mfma16(short8 a, short8 b, f32x4 c) {
  return __builtin_amdgcn_mfma_f32_16x16x32_bf16(a, b, c, 0, 0, 0);
}
__device__ __forceinline__ float rcpf(float x) { return __builtin_amdgcn_rcpf(x); }

// 5 exp + 3 rcp per unit (merged denominators); all quarter-rate ops explicit.
__device__ __forceinline__ float lstm_ew(float gi, float gf, float gg, float go, float& c) {
  float ei = __expf(-gi), ef = __expf(-gf), eg = __expf(-2.f * gg);
  float di = 1.f + ei, df = 1.f + ef, dg = 1.f + eg;
  float r1 = rcpf(di * dg);
  float si = r1 * dg;                    // sigmoid(gi)
  float tg = 2.f * (r1 * di) - 1.f;      // tanh(gg)
  c = rcpf(df) * c + si * tg;
  float eo = __expf(-go), ec = __expf(2.f * c);
  float do_ = 1.f + eo, dc = 1.f + ec;
  float r3 = rcpf(do_ * dc);
  float so = r3 * dc;                    // sigmoid(go)
  float th = 2.f * (r3 * do_) * ec - (2.f * (r3 * do_) - 1.f);  // see note
  // th simplification: tanh(c) = (ec-1)/(ec+1) = 2*ec/dc - (2/dc - 1)... use direct:
  th = 1.f - 2.f * (r3 * do_);           // = 1 - 2/dc = (ec-1)/(ec+1) = tanh(c)
  return so * th;
}

__device__ __forceinline__ short8 cvt8(f32x4 v0, f32x4 v1) {
  short8 o;
  o[0] = (short)f2bf(v0[0]); o[1] = (short)f2bf(v0[1]);
  o[2] = (short)f2bf(v0[2]); o[3] = (short)f2bf(v0[3]);
  o[4] = (short)f2bf(v1[0]); o[5] = (short)f2bf(v1[1]);
  o[6] = (short)f2bf(v1[2]); o[7] = (short)f2bf(v1[3]);
  return o;
}

__device__ __forceinline__ void bar_lds() {  // LDS-only barrier; vmem stays in flight
  asm volatile("s_waitcnt lgkmcnt(0)" ::: "memory");
  __builtin_amdgcn_s_barrier();
}

__device__ __forceinline__ void gload16(const void* g, void* l) {
  __builtin_amdgcn_global_load_lds(
      (const __attribute__((address_space(1))) void*)g,
      (__attribute__((address_space(3))) void*)l, 16, 0, 0);
}

// ---------------- prep: x image in LDS-tile layout ---------------------------
// word gid = ((bblk*1024 + t)*512 + i), i = r*32 + s; holds bf16x8 of
// x[bblk*16+r][t][k-chunk (s ^ (r&7))] * mask.
__global__ __launch_bounds__(256, 4) void prep_kernel(
    const float* __restrict__ x, const float* __restrict__ mask,
    unsigned short* __restrict__ img) {
  int gid = blockIdx.x * 256 + threadIdx.x;
  int i = gid & 511;
  int tt = (gid >> 9) & 1023;
  int bblk = gid >> 19;
  int r = i >> 5, s = i & 31, kc = s ^ (r & 7);
  int b = bblk * 16 + r;
  const f32x4* src = (const f32x4*)(x + ((size_t)b * T_ + tt) * E_ + kc * 8);
  float mk = mask[(size_t)b * T_ + tt];
  ((short8*)img)[gid] = cvt8(src[0] * mk, src[1] * mk);
}

// ---------------- rec: fused projection + recurrence --------------------------
// grid 64, 512 threads. group g = bid & 15, member m = bid >> 4.
template <bool PREP>
__global__ __launch_bounds__(512, 1) void rec_kernel(
    const float* __restrict__ x, const float* __restrict__ mask,
    const unsigned short* __restrict__ img,
    const float* __restrict__ WihF, const float* __restrict__ WhhF,
    const float* __restrict__ bF, const float* __restrict__ WihB,
    const float* __restrict__ WhhB, const float* __restrict__ bB,
    unsigned long long* __restrict__ Hbuf, float* __restrict__ hsum) {
  __shared__ __align__(16) short XS[2][16 * 256];  // x stage, parity dbuf (16KB)
  __shared__ __align__(16) short HS[16 * 256];     // h stage (8KB)
  __shared__ __align__(16) float gatesL[16 * 260]; // gates fp32, +4 pad

  const int bid = blockIdx.x;
  const int g = bid & 15, m = bid >> 4;
  const int d = g >> 3, bblk = g & 7;
  const int tid = threadIdx.x;
  const int w = tid >> 6, l = tid & 63, l15 = l & 15, l4 = l >> 4;
  const int sr = tid >> 5, sc = tid & 31;
  const int ej2 = sc * 2;
  const int gb = bblk * 16 + sr;

  const float* Wih = d ? WihB : WihF;
  const float* Whh = d ? WhhB : WhhF;
  const float* bias = d ? bB : bF;

  // weight fragments -> registers
  short8 wi[2][8], wh[2][8];
  float biasv[2];
#pragma unroll
  for (int i = 0; i < 2; ++i) {
    int cp = (2 * w + i) * 16 + l15;
    int gate = cp >> 6, ul = cp & 63;
    size_t nat = (size_t)(gate * 256 + m * 64 + ul);
    biasv[i] = bias[nat];
#pragma unroll
    for (int kb = 0; kb < 8; ++kb) {
      const f32x4* pi = (const f32x4*)(Wih + nat * E_ + kb * 32 + l4 * 8);
      wi[i][kb] = cvt8(pi[0], pi[1]);
      const f32x4* ph = (const f32x4*)(Whh + nat * H_ + kb * 32 + l4 * 8);
      wh[i][kb] = cvt8(ph[0], ph[1]);
    }
  }
  const int ub = m * 64 + ej2;

  // x image source pointer (bytes); one 8KB tile per t
  const int dstep = d ? -8192 : 8192;
  const char* gsrc = (const char*)img +
      ((size_t)(bblk * 1024 + (d ? (T_ - 1) : 0)) * 8192) + (size_t)tid * 16;

  // ---- prologue: HS=0; stage x_0 AND x_1; acc = bias + xg_0 ----
  ((int4*)HS)[tid] = (int4){0, 0, 0, 0};
  if constexpr (PREP) {
    gload16(gsrc, (char*)XS[0] + w * 1024);
    gload16(gsrc + dstep, (char*)XS[1] + w * 1024);
    gsrc += 2 * dstep;
  } else {
    int ts = d ? (T_ - 1) : 0;
    const f32x4* px = (const f32x4*)(x + ((size_t)gb * T_ + ts) * E_ + sc * 8);
    float mk = mask[(size_t)gb * T_ + ts];
    ((short8*)XS[0])[sr * 32 + (sc ^ (sr & 7))] = cvt8(px[0] * mk, px[1] * mk);
  }
  __syncthreads();  // drains gloads (vmcnt 0) + HS zeros visible
  f32x4 acc[2], accB[2];
  acc[0] = (f32x4){biasv[0], biasv[0], biasv[0], biasv[0]};
  acc[1] = (f32x4){biasv[1], biasv[1], biasv[1], biasv[1]};
  accB[0] = (f32x4){0.f, 0.f, 0.f, 0.f};
  accB[1] = (f32x4){0.f, 0.f, 0.f, 0.f};
#pragma unroll
  for (int kp = 0; kp < 4; ++kp) {
    short8 a0 = ((short8*)XS[0])[l15 * 32 + ((kp * 8 + l4) ^ (l15 & 7))];
    acc[0] = mfma16(a0, wi[0][2 * kp], acc[0]);
    acc[1] = mfma16(a0, wi[1][2 * kp], acc[1]);
    short8 a1 = ((short8*)XS[0])[l15 * 32 + ((kp * 8 + 4 + l4) ^ (l15 & 7))];
    accB[0] = mfma16(a1, wi[0][2 * kp + 1], accB[0]);
    accB[1] = mfma16(a1, wi[1][2 * kp + 1], accB[1]);
  }
  __syncthreads();  // XS[0] fully consumed before loop's first gload overwrites it

  float cs0 = 0.f, cs1 = 0.f, hs0 = 0.f, hs1 = 0.f;

  for (int t = 0; t < T_; ++t) {
    const bool more = (t + 1 < T_);

    // prefetch x_{t+2} (PREP): lands in XS[t&1]; never drained in-loop —
    // retirement is implied by this step's poll vmcnt (in-order) + end barrier.
    if constexpr (PREP) {
      if (t + 2 < T_) {
        gload16(gsrc, (char*)XS[t & 1] + w * 1024);
        gsrc += dstep;
      }
    }
    f32x4 xv0, xv1;
    float mk = 0.f;
    if constexpr (!PREP) {
      if (more) {
        int ts = d ? (T_ - 2 - t) : (t + 1);
        const f32x4* px = (const f32x4*)(x + ((size_t)gb * T_ + ts) * E_ + sc * 8);
        xv0 = px[0]; xv1 = px[1];
        mk = mask[(size_t)gb * T_ + ts];
      }
    }

    // hh product into acc (acc holds bias + xg_t); HS holds h_t (zeros at t=0)
#pragma unroll
    for (int kp = 0; kp < 4; ++kp) {
      short8 a0 = ((short8*)HS)[l15 * 32 + ((kp * 8 + l4) ^ (l15 & 7))];
      acc[0] = mfma16(a0, wh[0][2 * kp], acc[0]);
      acc[1] = mfma16(a0, wh[1][2 * kp], acc[1]);
      short8 a1 = ((short8*)HS)[l15 * 32 + ((kp * 8 + 4 + l4) ^ (l15 & 7))];
      accB[0] = mfma16(a1, wh[0][2 * kp + 1], accB[0]);
      accB[1] = mfma16(a1, wh[1][2 * kp + 1], accB[1]);
    }

    // gates -> LDS. D layout: row(batch)=l4*4+r, col'=(2w+i)*16+l15
#pragma unroll
    for (int i = 0; i < 2; ++i)
#pragma unroll
      for (int r = 0; r < 4; ++r)
        gatesL[(l4 * 4 + r) * 260 + (2 * w + i) * 16 + l15] = acc[i][r] + accB[i][r];
    bar_lds();  // B1: gates visible (lgkm only)

    // elementwise (bias already folded into acc init)
    const float* gp = &gatesL[sr * 260 + ej2];
    f32x2 gI = *(const f32x2*)(gp);
    f32x2 gF = *(const f32x2*)(gp + 64);
    f32x2 gG = *(const f32x2*)(gp + 128);
    f32x2 gO = *(const f32x2*)(gp + 192);
    float h0 = lstm_ew(gI[0], gF[0], gG[0], gO[0], cs0);
    float h1 = lstm_ew(gI[1], gF[1], gG[1], gO[1], cs1);
    hs0 += h0;
    hs1 += h1;

    if (more) {
      const unsigned tag = (unsigned)(t + 1);
      const size_t base = ((size_t)g * 2 + (tag & 1)) * 16;

      // publish own slice (fire-and-forget)
      unsigned pay;
      asm("v_cvt_pk_bf16_f32 %0, %1, %2" : "=v"(pay) : "v"(h0), "v"(h1));
      unsigned long long word = (((unsigned long long)tag) << 32) | (unsigned long long)pay;
      __hip_atomic_store(&Hbuf[(base + sr) * 128 + m * 32 + sc], word,
                         __ATOMIC_RELAXED, __HIP_MEMORY_SCOPE_AGENT);
      asm volatile("" ::: "memory");  // keep store before polls (ordering proof)

      if constexpr (!PREP) {
        ((short8*)XS[(t + 1) & 1])[sr * 32 + (sc ^ (sr & 7))] = cvt8(xv0 * mk, xv1 * mk);
        bar_lds();  // XS visible (PREP path: staged 2 steps ago, already guaranteed)
      }

      // acc = bias + xg_{t+1} (fills publish->visibility window)
      acc[0] = (f32x4){biasv[0], biasv[0], biasv[0], biasv[0]};
      acc[1] = (f32x4){biasv[1], biasv[1], biasv[1], biasv[1]};
      accB[0] = (f32x4){0.f, 0.f, 0.f, 0.f};
      accB[1] = (f32x4){0.f, 0.f, 0.f, 0.f};
      const short8* xsN = (const short8*)XS[(t + 1) & 1];
#pragma unroll
      for (int kp = 0; kp < 4; ++kp) {
        short8 a0 = xsN[l15 * 32 + ((kp * 8 + l4) ^ (l15 & 7))];
        acc[0] = mfma16(a0, wi[0][2 * kp], acc[0]);
        acc[1] = mfma16(a0, wi[1][2 * kp], acc[1]);
        short8 a1 = xsN[l15 * 32 + ((kp * 8 + 4 + l4) ^ (l15 & 7))];
        accB[0] = mfma16(a1, wi[0][2 * kp + 1], accB[0]);
        accB[1] = mfma16(a1, wi[1][2 * kp + 1], accB[1]);
      }

      // poll peers' h_{t+1}: batched issue + parallel retry rounds
      const unsigned long long* rp = &Hbuf[(base + sr) * 128 + sc * 4];
      unsigned long long vv[4];
#pragma unroll
      for (int j = 0; j < 4; ++j)
        vv[j] = __hip_atomic_load(&rp[j], __ATOMIC_RELAXED, __HIP_MEMORY_SCOPE_AGENT);
      asm volatile("" ::: "memory");
      for (;;) {
        bool ok = true;
#pragma unroll
        for (int j = 0; j < 4; ++j) ok &= ((unsigned)(vv[j] >> 32) == tag);
        if (ok) break;
#pragma unroll
        for (int j = 0; j < 4; ++j)
          if ((unsigned)(vv[j] >> 32) != tag)
            vv[j] = __hip_atomic_load(&rp[j], __ATOMIC_RELAXED, __HIP_MEMORY_SCOPE_AGENT);
        asm volatile("" ::: "memory");
      }
      int4 hw;
      hw.x = (int)(unsigned)vv[0]; hw.y = (int)(unsigned)vv[1];
      hw.z = (int)(unsigned)vv[2]; hw.w = (int)(unsigned)vv[3];
      *(int4*)((char*)HS + (size_t)(sr * 32 + (sc ^ (sr & 7))) * 16) = hw;
      bar_lds();  // B2: HS visible; XS[(t+1)&1] fully read (lgkm only)
    }
  }

  hsum[((size_t)d * B_ + gb) * H_ + ub] = hs0;
  hsum[((size_t)d * B_ + gb) * H_ + ub + 1] = hs1;
}

// ---------------- head: linear ----------------------------------------------
__global__ __launch_bounds__(256, 1) void head_kernel(
    const float* __restrict__ hsum, const float* __restrict__ Wlin,
    const float* __restrict__ blin, float* __restrict__ out) {
  int tid = threadIdx.x;  // 256 = 128 b x 2 c
  int b = tid >> 1, c = tid & 1;
  const f32x4* hf = (const f32x4*)(hsum + (size_t)b * H_);
  const f32x4* hbk = (const f32x4*)(hsum + (size_t)B_ * H_ + (size_t)b * H_);
  const f32x4* wl = (const f32x4*)(Wlin + (size_t)c * 512);
  float s = 0.f;
  for (int j = 0; j < 64; ++j) {
    f32x4 a = hf[j], ww = wl[j];
    s += a[0] * ww[0] + a[1] * ww[1] + a[2] * ww[2] + a[3] * ww[3];
  }
  for (int j = 0; j < 64; ++j) {
    f32x4 a = hbk[j], ww = wl[64 + j];
    s += a[0] * ww[0] + a[1] * ww[1] + a[2] * ww[2] + a[3] * ww[3];
  }
  out[tid] = s * (1.0f / 1024.0f) + blin[c];
}

// ---------------- launch -----------------------------------------------------
extern "C" void kernel_launch(void* const* d_in, const int* in_sizes, int n_in,
                              void* d_out, int out_size, void* d_ws, size_t ws_size,
                              hipStream_t stream) {
  const float* emb = (const float*)d_in[0];
  const float* mask = (const float*)d_in[1];
  const float* Wih_f = (const float*)d_in[2];
  const float* Whh_f = (const float*)d_in[3];
  const float* b_f = (const float*)d_in[4];
  const float* Wih_b = (const float*)d_in[5];
  const float* Whh_b = (const float*)d_in[6];
  const float* b_b = (const float*)d_in[7];
  const float* Wlin = (const float*)d_in[8];
  const float* blin = (const float*)d_in[9];
  float* out = (float*)d_out;

  const size_t HBUF_BYTES = (size_t)16 * 2 * 16 * 128 * 8;    // 512 KiB
  const size_t HSUM_BYTES = (size_t)2 * B_ * H_ * 4;          // 256 KiB
  const size_t IMG_BYTES = (size_t)8 * 1024 * 512 * 16;       // 64 MiB
  if (ws_size < HBUF_BYTES + HSUM_BYTES) return;
  const bool prep = ws_size >= HBUF_BYTES + HSUM_BYTES + IMG_BYTES;

  char* ws = (char*)d_ws;
  unsigned long long* Hbuf = (unsigned long long*)ws;
  float* hsum = (float*)(ws + HBUF_BYTES);
  unsigned short* img = (unsigned short*)(ws + HBUF_BYTES + HSUM_BYTES);

  hipMemsetAsync(Hbuf, 0, HBUF_BYTES, stream);  // tags start at 1; replay-safe
  if (prep) {
    prep_kernel<<<16384, 256, 0, stream>>>(emb, mask, img);
    rec_kernel<true><<<64, 512, 0, stream>>>(emb, mask, img, Wih_f, Whh_f, b_f,
                                             Wih_b, Whh_b, b_b, Hbuf, hsum);
  } else {
    rec_kernel<false><<<64, 512, 0, stream>>>(emb, mask, img, Wih_f, Whh_f, b_f,
                                              Wih_b, Whh_b, b_b, Hbuf, hsum);
  }
  head_kernel<<<1, 256, 0, stream>>>(hsum, Wlin, blin, out);
}